// Round 5
// baseline (619.952 us; speedup 1.0000x reference)
//
#include <hip/hip_runtime.h>
#include <stdint.h>
#include <stddef.h>

// VectorQuantization — N=32768, K=8192, D=256 fp32 -> int32 argmin.
// Round 5: occupancy attack. Round 4 sat at the m97 plateau (MfmaUtil 48%,
// occupancy 21%, 2 blocks/CU): barrier vmcnt-drains exposed. BK 64->32 cuts
// LDS to 32KB; __launch_bounds__(256,4) -> 4 blocks/CU -> 1024 resident
// blocks == grid size exactly (single co-resident generation, zero tail),
// drains hidden by 3 partner blocks (m114 overlap). Same verified split-f16
// 3-pass MFMA + XOR-swizzled DMA staging as round 4.
//   x.c = xh*ch + (xh*2^-11)*(cl*2^11) + (xl*2^11)*(ch*2^-11)
// argmin_k(c2[k] - 2*x.c_k); strict-< ascending merge == np first-min rule.
// SPLITK=4, split=blk&3, XCD=blk%8 -> each XCD L2 holds one 2MB code chunk.
// Fallback to round-3 kernel if ws_size < 43MB.

#define N_PTS 32768
#define K_CB  8192
#define D_DIM 256
#define TM 128
#define TN 128
#define SPLITK 4
#define KCHUNK (K_CB / SPLITK)   // 2048
#define NTILES (KCHUNK / TN)     // 16

// ws layout (byte offsets; all 16B-aligned)
#define WS_XH   0
#define WS_XL   (WS_XH + N_PTS * D_DIM * 2)
#define WS_CH   (WS_XL + N_PTS * D_DIM * 2)
#define WS_CL   (WS_CH + K_CB * D_DIM * 2)
#define WS_C2   (WS_CL + K_CB * D_DIM * 2)
#define WS_PD   (WS_C2 + K_CB * 4)
#define WS_PI   (WS_PD + SPLITK * N_PTS * 4)
#define WS_END  (WS_PI + SPLITK * N_PTS * 4)   // 43,024,384 B

typedef _Float16 half4v __attribute__((ext_vector_type(4)));
typedef _Float16 half8v __attribute__((ext_vector_type(8)));
typedef float    f32x4  __attribute__((ext_vector_type(4)));

__device__ __forceinline__ void gld16(const void* g, void* l) {
    __builtin_amdgcn_global_load_lds(
        (const __attribute__((address_space(1))) void*)g,
        (__attribute__((address_space(3))) void*)l, 16, 0, 0);
}

// ---------------- preprocessing ----------------

__global__ void __launch_bounds__(256)
split_kernel(const float* __restrict__ src, _Float16* __restrict__ h_out,
             _Float16* __restrict__ l_out) {
    const int i = blockIdx.x * 256 + threadIdx.x;   // one float4 per thread
    const float4 v = ((const float4*)src)[i];
    half4v h = {(_Float16)v.x, (_Float16)v.y, (_Float16)v.z, (_Float16)v.w};
    half4v l = {(_Float16)((v.x - (float)h[0]) * 2048.0f),
                (_Float16)((v.y - (float)h[1]) * 2048.0f),
                (_Float16)((v.z - (float)h[2]) * 2048.0f),
                (_Float16)((v.w - (float)h[3]) * 2048.0f)};
    *(half4v*)(h_out + (size_t)i * 4) = h;
    *(half4v*)(l_out + (size_t)i * 4) = l;
}

// codebook: split + norm fused, one wave per row
__global__ void __launch_bounds__(256)
csplit_norm(const float* __restrict__ vecs, _Float16* __restrict__ h_out,
            _Float16* __restrict__ l_out, float* __restrict__ c2) {
    const int row  = (blockIdx.x * 256 + threadIdx.x) >> 6;
    const int lane = threadIdx.x & 63;
    const float4 v = ((const float4*)(vecs + (size_t)row * D_DIM))[lane];
    half4v h = {(_Float16)v.x, (_Float16)v.y, (_Float16)v.z, (_Float16)v.w};
    half4v l = {(_Float16)((v.x - (float)h[0]) * 2048.0f),
                (_Float16)((v.y - (float)h[1]) * 2048.0f),
                (_Float16)((v.z - (float)h[2]) * 2048.0f),
                (_Float16)((v.w - (float)h[3]) * 2048.0f)};
    *(half4v*)(h_out + (size_t)row * D_DIM + lane * 4) = h;
    *(half4v*)(l_out + (size_t)row * D_DIM + lane * 4) = l;
    float s = v.x * v.x + v.y * v.y + v.z * v.z + v.w * v.w;
#pragma unroll
    for (int off = 32; off > 0; off >>= 1) s += __shfl_down(s, off, 64);
    if (lane == 0) c2[row] = s;
}

// ---------------- fast main kernel ----------------

__global__ void __launch_bounds__(256, 4)
vq_main_fast(const _Float16* __restrict__ xh_g, const _Float16* __restrict__ xl_g,
             const _Float16* __restrict__ ch_g, const _Float16* __restrict__ cl_g,
             const float* __restrict__ c2, float* __restrict__ pd, int* __restrict__ pi) {
    // regions: xh [0,8K), xl [8K,16K), ch [16K,24K), cl [24K,32K); row = 64B
    __shared__ __align__(16) char lds[32768];

    const int t    = threadIdx.x;
    const int lane = t & 63;
    const int wv   = t >> 6;
    const int wy   = wv >> 1, wx = wv & 1;   // wave quadrant of 128x128
    const int fr   = lane & 15;              // row/col within 16x16 tile
    const int g    = lane >> 4;              // k-group 0..3

    const int split = blockIdx.x & (SPLITK - 1);
    const int pbase = (blockIdx.x >> 2) * TM;
    const int kbase = split * KCHUNK;

    // staging (BK=32 halves = 64B/row): one gld16 covers 16 rows x 4 slots.
    // lane (r16,s) reads logical slot s^(r16&3) -> LDS phys slot p holds
    // logical p^(row&3) (XOR swizzle), DMA dest stays lane-contiguous.
    const int rowoff = (lane >> 2) * (D_DIM * 2) + (((lane & 3) ^ ((lane >> 2) & 3)) << 4);
    const char* xh_w = (const char*)xh_g + (size_t)(pbase + wv * 32) * (D_DIM * 2) + rowoff;
    const char* xl_w = (const char*)xl_g + (size_t)(pbase + wv * 32) * (D_DIM * 2) + rowoff;
    char* ldsA_h = lds +         wv * 2048;   // wave-uniform DMA bases
    char* ldsA_l = lds +  8192 + wv * 2048;
    char* ldsB_h = lds + 16384 + wv * 2048;
    char* ldsB_l = lds + 24576 + wv * 2048;

    // fragment LDS byte offsets: row*64 + swizzled 16B granule (g ^ (row&3))
    int aoff[4], boff[4];
#pragma unroll
    for (int i = 0; i < 4; ++i) {
        aoff[i] = (wy * 64 + i * 16 + fr) * 64 + ((g ^ (fr & 3)) << 4);
        boff[i] = 16384 + (wx * 64 + i * 16 + fr) * 64 + ((g ^ (fr & 3)) << 4);
    }

    float best[16];
    int   bidx[16];
#pragma unroll
    for (int i = 0; i < 16; ++i) { best[i] = 3.4e38f; bidx[i] = 0; }

    for (int kt = 0; kt < NTILES; ++kt) {
        const int ktbase = kbase + kt * TN;
        const char* ch_w = (const char*)ch_g + (size_t)(ktbase + wv * 32) * (D_DIM * 2) + rowoff;
        const char* cl_w = (const char*)cl_g + (size_t)(ktbase + wv * 32) * (D_DIM * 2) + rowoff;

        f32x4 acc[4][4];
#pragma unroll
        for (int i = 0; i < 4; ++i)
#pragma unroll
            for (int j = 0; j < 4; ++j) {
                f32x4 z = {0.f, 0.f, 0.f, 0.f};
                acc[i][j] = z;
            }

#pragma unroll 1
        for (int dkc = 0; dkc < 8; ++dkc) {      // 32-half K chunks
            const int gofs = dkc * 64;           // byte offset into each row
            __syncthreads();                     // readers of prev chunk done
#pragma unroll
            for (int q = 0; q < 2; ++q) {        // 16 rows/inst, 32 rows/wave
                gld16(xh_w + q * 8192 + gofs, ldsA_h + q * 1024);
                gld16(xl_w + q * 8192 + gofs, ldsA_l + q * 1024);
                gld16(ch_w + q * 8192 + gofs, ldsB_h + q * 1024);
                gld16(cl_w + q * 8192 + gofs, ldsB_l + q * 1024);
            }
            __syncthreads();                     // barrier drains vmcnt
            half8v a1[4], a2[4], a3[4];
#pragma unroll
            for (int i = 0; i < 4; ++i) {
                const char* p = lds + aoff[i];
                a1[i] = *(const half8v*)p;               // xh
                a3[i] = *(const half8v*)(p + 8192);      // xl*2^11
                a2[i] = a1[i] * (_Float16)4.8828125e-4f; // xh*2^-11
            }
#pragma unroll
            for (int j = 0; j < 4; ++j) {
                const char* p = lds + boff[j];
                half8v b1 = *(const half8v*)p;              // ch
                half8v b2 = *(const half8v*)(p + 8192);     // cl*2^11
                half8v b3 = b1 * (_Float16)4.8828125e-4f;   // ch*2^-11
#pragma unroll
                for (int i = 0; i < 4; ++i) {
                    acc[i][j] = __builtin_amdgcn_mfma_f32_16x16x32_f16(a1[i], b1, acc[i][j], 0, 0, 0);
                    acc[i][j] = __builtin_amdgcn_mfma_f32_16x16x32_f16(a2[i], b2, acc[i][j], 0, 0, 0);
                    acc[i][j] = __builtin_amdgcn_mfma_f32_16x16x32_f16(a3[i], b3, acc[i][j], 0, 0, 0);
                }
            }
        }

        // merge tile into running argmin; ascending j + strict < == np first-min
#pragma unroll
        for (int j = 0; j < 4; ++j) {
            const int cg = ktbase + wx * 64 + j * 16 + fr;
            const float c2v = c2[cg];
#pragma unroll
            for (int i = 0; i < 4; ++i)
#pragma unroll
                for (int r = 0; r < 4; ++r) {
                    const float v = fmaf(-2.0f, acc[i][j][r], c2v);
                    const int s = i * 4 + r;
                    if (v < best[s]) { best[s] = v; bidx[s] = cg; }
                }
        }
    }

    // reduce across the 16 lanes holding each point row, then the 2 wave-cols
    __syncthreads();
    float* rd = (float*)lds;          // 128 x 2 floats
    int*   ri = (int*)lds + 256;      // 128 x 2 ints
#pragma unroll
    for (int i = 0; i < 4; ++i)
#pragma unroll
        for (int r = 0; r < 4; ++r) {
            float bv = best[i * 4 + r];
            int   bi = bidx[i * 4 + r];
#pragma unroll
            for (int off = 1; off < 16; off <<= 1) {
                const float ov = __shfl_xor(bv, off, 64);
                const int   oi = __shfl_xor(bi, off, 64);
                if (ov < bv || (ov == bv && oi < bi)) { bv = ov; bi = oi; }
            }
            if (fr == 0) {
                const int rowl = wy * 64 + i * 16 + g * 4 + r;
                rd[rowl * 2 + wx] = bv;
                ri[rowl * 2 + wx] = bi;
            }
        }
    __syncthreads();
    if (t < TM) {
        float b0 = rd[t * 2];
        int   i0 = ri[t * 2];
        const float b1 = rd[t * 2 + 1];
        const int   i1 = ri[t * 2 + 1];
        if (b1 < b0 || (b1 == b0 && i1 < i0)) { b0 = b1; i0 = i1; }
        pd[split * N_PTS + pbase + t] = b0;
        pi[split * N_PTS + pbase + t] = i0;
    }
}

// ---------------- fallback (round-3, passing) ----------------

#define FBK 32
#define FLS (FBK + 4)

__device__ inline half8v load8(const _Float16* p) {
    half4v a = *(const half4v*)p;
    half4v b = *(const half4v*)(p + 4);
    return __builtin_shufflevector(a, b, 0, 1, 2, 3, 4, 5, 6, 7);
}

struct Trip { _Float16 h, s2, l2; };

__device__ inline Trip cvt3(float v) {
    Trip t;
    _Float16 hh = (_Float16)v;
    float hf = (float)hh;
    t.h  = hh;
    t.s2 = (_Float16)(hf * 4.8828125e-4f);
    t.l2 = (_Float16)((v - hf) * 2048.0f);
    return t;
}

__global__ void __launch_bounds__(256, 2)
vq_main_v3(const float* __restrict__ x, const float* __restrict__ vecs,
           const float* __restrict__ c2, float* __restrict__ pd, int* __restrict__ pi) {
    __shared__ _Float16 lds[6 * TM * FLS];
    _Float16* xh  = lds;
    _Float16* xs2 = lds + 1 * TM * FLS;
    _Float16* xl2 = lds + 2 * TM * FLS;
    _Float16* ch  = lds + 3 * TM * FLS;
    _Float16* cl2 = lds + 4 * TM * FLS;
    _Float16* cs2 = lds + 5 * TM * FLS;

    const int t     = threadIdx.x;
    const int split = blockIdx.x & (SPLITK - 1);
    const int pbase = (blockIdx.x >> 2) * TM;
    const int kbase = split * KCHUNK;

    const int lane = t & 63;
    const int wv   = t >> 6;
    const int wy   = wv >> 1, wx = wv & 1;
    const int fr   = lane & 15;
    const int g    = lane >> 4;
    const int kb   = g * 8;

    const int srow = t >> 3;
    const int sc4  = (t & 7) * 4;

    float best[16];
    int   bidx[16];
#pragma unroll
    for (int i = 0; i < 16; ++i) { best[i] = 3.4e38f; bidx[i] = 0; }

    for (int kt = 0; kt < NTILES; ++kt) {
        const int ktbase = kbase + kt * TN;
        f32x4 acc[4][4];
#pragma unroll
        for (int i = 0; i < 4; ++i)
#pragma unroll
            for (int j = 0; j < 4; ++j) {
                f32x4 z = {0.f, 0.f, 0.f, 0.f};
                acc[i][j] = z;
            }
        for (int dk = 0; dk < D_DIM; dk += FBK) {
            __syncthreads();
#pragma unroll
            for (int p = 0; p < 4; ++p) {
                const int row = srow + p * 32;
                const float4 v = *(const float4*)&x[(size_t)(pbase + row) * D_DIM + dk + sc4];
                const Trip t0 = cvt3(v.x), t1 = cvt3(v.y), t2 = cvt3(v.z), t3 = cvt3(v.w);
                half4v h  = {t0.h,  t1.h,  t2.h,  t3.h};
                half4v s2 = {t0.s2, t1.s2, t2.s2, t3.s2};
                half4v l2 = {t0.l2, t1.l2, t2.l2, t3.l2};
                *(half4v*)&xh [row * FLS + sc4] = h;
                *(half4v*)&xs2[row * FLS + sc4] = s2;
                *(half4v*)&xl2[row * FLS + sc4] = l2;
                const float4 w = *(const float4*)&vecs[(size_t)(ktbase + row) * D_DIM + dk + sc4];
                const Trip u0 = cvt3(w.x), u1 = cvt3(w.y), u2 = cvt3(w.z), u3 = cvt3(w.w);
                half4v hc = {u0.h,  u1.h,  u2.h,  u3.h};
                half4v sc = {u0.s2, u1.s2, u2.s2, u3.s2};
                half4v lc = {u0.l2, u1.l2, u2.l2, u3.l2};
                *(half4v*)&ch [row * FLS + sc4] = hc;
                *(half4v*)&cs2[row * FLS + sc4] = sc;
                *(half4v*)&cl2[row * FLS + sc4] = lc;
            }
            __syncthreads();
            half8v a1[4], a2[4], a3[4], b1[4], b2[4], b3[4];
#pragma unroll
            for (int i = 0; i < 4; ++i) {
                const int aoff = (wy * 64 + i * 16 + fr) * FLS + kb;
                a1[i] = load8(&xh [aoff]);
                a2[i] = load8(&xs2[aoff]);
                a3[i] = load8(&xl2[aoff]);
                const int boff2 = (wx * 64 + i * 16 + fr) * FLS + kb;
                b1[i] = load8(&ch [boff2]);
                b2[i] = load8(&cl2[boff2]);
                b3[i] = load8(&cs2[boff2]);
            }
#pragma unroll
            for (int i = 0; i < 4; ++i)
#pragma unroll
                for (int j = 0; j < 4; ++j) {
                    acc[i][j] = __builtin_amdgcn_mfma_f32_16x16x32_f16(a1[i], b1[j], acc[i][j], 0, 0, 0);
                    acc[i][j] = __builtin_amdgcn_mfma_f32_16x16x32_f16(a2[i], b2[j], acc[i][j], 0, 0, 0);
                    acc[i][j] = __builtin_amdgcn_mfma_f32_16x16x32_f16(a3[i], b3[j], acc[i][j], 0, 0, 0);
                }
        }
#pragma unroll
        for (int j = 0; j < 4; ++j) {
            const int cg = ktbase + wx * 64 + j * 16 + fr;
            const float c2v = c2[cg];
#pragma unroll
            for (int i = 0; i < 4; ++i)
#pragma unroll
                for (int r = 0; r < 4; ++r) {
                    const float v = fmaf(-2.0f, acc[i][j][r], c2v);
                    const int s = i * 4 + r;
                    if (v < best[s]) { best[s] = v; bidx[s] = cg; }
                }
        }
    }
    __syncthreads();
    float* rd = (float*)lds;
    int*   ri = (int*)lds + 256;
#pragma unroll
    for (int i = 0; i < 4; ++i)
#pragma unroll
        for (int r = 0; r < 4; ++r) {
            float bv = best[i * 4 + r];
            int   bi = bidx[i * 4 + r];
#pragma unroll
            for (int off = 1; off < 16; off <<= 1) {
                const float ov = __shfl_xor(bv, off, 64);
                const int   oi = __shfl_xor(bi, off, 64);
                if (ov < bv || (ov == bv && oi < bi)) { bv = ov; bi = oi; }
            }
            if (fr == 0) {
                const int rowl = wy * 64 + i * 16 + g * 4 + r;
                rd[rowl * 2 + wx] = bv;
                ri[rowl * 2 + wx] = bi;
            }
        }
    __syncthreads();
    if (t < TM) {
        float b0 = rd[t * 2];
        int   i0 = ri[t * 2];
        const float b1 = rd[t * 2 + 1];
        const int   i1 = ri[t * 2 + 1];
        if (b1 < b0 || (b1 == b0 && i1 < i0)) { b0 = b1; i0 = i1; }
        pd[split * N_PTS + pbase + t] = b0;
        pi[split * N_PTS + pbase + t] = i0;
    }
}

// ---------------- combine ----------------

__global__ void __launch_bounds__(256)
vq_combine(const float* __restrict__ pd, const int* __restrict__ pi,
           int* __restrict__ out) {
    const int p = blockIdx.x * 256 + threadIdx.x;
    float bb = pd[p];
    int   bi = pi[p];
#pragma unroll
    for (int s = 1; s < SPLITK; ++s) {
        const float v  = pd[s * N_PTS + p];
        const int   vi = pi[s * N_PTS + p];
        if (v < bb || (v == bb && vi < bi)) { bb = v; bi = vi; }
    }
    out[p] = bi;
}

extern "C" void kernel_launch(void* const* d_in, const int* in_sizes, int n_in,
                              void* d_out, int out_size, void* d_ws, size_t ws_size,
                              hipStream_t stream) {
    const float* x    = (const float*)d_in[0];
    const float* vecs = (const float*)d_in[1];
    int* out = (int*)d_out;
    char* ws = (char*)d_ws;

    if (ws_size >= (size_t)WS_END) {
        _Float16* xh = (_Float16*)(ws + WS_XH);
        _Float16* xl = (_Float16*)(ws + WS_XL);
        _Float16* ch = (_Float16*)(ws + WS_CH);
        _Float16* cl = (_Float16*)(ws + WS_CL);
        float* c2 = (float*)(ws + WS_C2);
        float* pd = (float*)(ws + WS_PD);
        int*   pi = (int*)(ws + WS_PI);

        hipLaunchKernelGGL(split_kernel, dim3(N_PTS * D_DIM / 4 / 256), dim3(256), 0, stream,
                           x, xh, xl);
        hipLaunchKernelGGL(csplit_norm, dim3(K_CB / 4), dim3(256), 0, stream,
                           vecs, ch, cl, c2);
        hipLaunchKernelGGL(vq_main_fast, dim3((N_PTS / TM) * SPLITK), dim3(256), 0, stream,
                           xh, xl, ch, cl, c2, pd, pi);
        hipLaunchKernelGGL(vq_combine, dim3(N_PTS / 256), dim3(256), 0, stream,
                           pd, pi, out);
    } else {
        float* c2 = (float*)ws;
        float* pd = (float*)ws + K_CB;
        int*   pi = (int*)((float*)ws + K_CB + SPLITK * N_PTS);
        hipLaunchKernelGGL(csplit_norm, dim3(K_CB / 4), dim3(256), 0, stream,
                           vecs, (_Float16*)((float*)ws + K_CB + 2 * SPLITK * N_PTS),
                           (_Float16*)((float*)ws + K_CB + 2 * SPLITK * N_PTS) + K_CB * D_DIM, c2);
        hipLaunchKernelGGL(vq_main_v3, dim3((N_PTS / TM) * SPLITK), dim3(256), 0, stream,
                           x, vecs, c2, pd, pi);
        hipLaunchKernelGGL(vq_combine, dim3(N_PTS / 256), dim3(256), 0, stream,
                           pd, pi, out);
    }
}